// Round 11
// baseline (13123.727 us; speedup 1.0000x reference)
//
#include <hip/hip_runtime.h>
#include <math.h>

// DARTS recurrent cell on MI355X — persistent cooperative kernel, v11.
// Evidence through v10: dur == beyond-L2 bytes / ~2.2-2.6 TB/s (fabric ceiling
// for this pattern). So v11 cuts BYTES and sync serialization:
//  1) nt-hints on W0+Ws3..7 (9.45 MB/XCD streaming) -> Ws0/1/2 (3.15 MB/XCD)
//     stay L2-resident across steps: 88 -> ~63 MB/step beyond-L2.
//  2) per-wave polling for L2-L5 (no post-poll barrier; FA loads issue right
//     after each wave's own poll). One acquire/step unchanged (wave15 + bar).
//  3) arena stride 516 floats (was 512): kills 16-way rsum bank conflict.

typedef __attribute__((ext_vector_type(8))) _Float16 half8;
typedef __attribute__((ext_vector_type(4))) float f32x4;
typedef __attribute__((ext_vector_type(8))) unsigned short us8;

#define NH 1024
#define SCALE 2048.f
#define INVS  (1.f/2048.f)
#define WF_BYTES 83886080ull
#define FA_BYTES 1572864ull
#define T_STEPS  256
#define AST 516                      // arena stride (floats) per wave

#define LBAR() asm volatile("s_waitcnt lgkmcnt(0)\n\ts_barrier" ::: "memory")

__device__ __forceinline__ float sigf(float x){ return 1.f/(1.f+__expf(-x)); }
__device__ __forceinline__ void limbs2(float x, _Float16& a, _Float16& b){
    a = (_Float16)x; b = (_Float16)((x - (float)a)*SCALE);
}

// ---------------- weight pre-swizzle (identical to v4-v10, proven) -----------
struct Pre { const float* W0; const float* Ws; unsigned short* wf; };

__global__ __launch_bounds__(256) void preconv(Pre d) {
    int gid  = blockIdx.x * 4 + (threadIdx.x >> 6);
    int lane = threadIdx.x & 63;
    const float* W; unsigned short* dst; int nks, cg, ks;
    if (gid < 8192) {
        W = d.W0; dst = d.wf; nks = 64; cg = gid >> 6; ks = gid & 63;
    } else {
        int g = gid - 8192; int mm = g >> 12; int wi = g & 4095;
        W   = d.Ws + (size_t)mm * (1024 * 2048);
        dst = d.wf + 8388608ull + (size_t)mm * 4194304ull;
        nks = 32; cg = wi >> 5; ks = wi & 31;
    }
    int c  = cg * 16 + (lane & 15);
    int kb = ks * 32 + (lane >> 4) * 8;
    half8 h0, h1;
    #pragma unroll
    for (int j = 0; j < 8; ++j) {
        _Float16 p, q; limbs2(W[(size_t)(kb + j) * 2048 + c], p, q);
        h0[j] = p; h1[j] = q;
    }
    unsigned short* o = dst + ((size_t)cg * nks + ks) * 1024 + lane * 8;
    *(half8*)o         = h0;
    *(half8*)(o + 512) = h1;
}

// -------- init: hidden -> interleaved H frag plane; flag init ----------------
__global__ __launch_bounds__(256) void initk(const float* hidden, char* fa, unsigned* flags) {
    int gid = blockIdx.x * 256 + threadIdx.x;
    if (gid < 1536) flags[gid] = (gid < 256) ? 1u : 0u;
    #pragma unroll
    for (int e = 0; e < 4; ++e) {
        int i = gid * 4 + e;
        int row = i >> 10, col = i & 1023;
        int rt = row >> 4, rowf = row & 15;
        int ksp = col >> 5, kin = col & 31;
        int lanep = (kin >> 3) * 16 + rowf;
        size_t off = (size_t)rt * 65536 + ((size_t)ksp * 64 + lanep) * 32 + (kin & 7) * 4;
        _Float16 u0, u1; limbs2(hidden[i], u0, u1);
        unsigned pk = (unsigned)__builtin_bit_cast(unsigned short, u0) |
                      ((unsigned)__builtin_bit_cast(unsigned short, u1) << 16);
        *(unsigned*)(fa + off) = pk;
    }
}

// ------------------------------ device helpers -------------------------------
__device__ __forceinline__ void aload(const char* fa, int ks, int lane, half8& a0, half8& a1) {
    const char* p = fa + ((size_t)ks * 64 + lane) * 32;
    us8 q0 = *(const us8*)p;
    us8 q1 = *(const us8*)(p + 16);
    a0 = __builtin_bit_cast(half8, __builtin_shufflevector(q0, q1, 0,2,4,6,8,10,12,14));
    a1 = __builtin_bit_cast(half8, __builtin_shufflevector(q0, q1, 1,3,5,7,9,11,13,15));
}
template<int NT>
__device__ __forceinline__ half8 ldw(const unsigned short* p) {
    if constexpr (NT) {
        us8 v = __builtin_nontemporal_load((const us8*)p);
        return __builtin_bit_cast(half8, v);
    }
    return *(const half8*)p;
}
__device__ __forceinline__ void mfma6(half8 a0, half8 a1, half8 w0, half8 w1,
                                      f32x4& x0, f32x4& x1) {
    x0 = __builtin_amdgcn_mfma_f32_16x16x32_f16(a0, w0, x0, 0, 0, 0);
    x1 = __builtin_amdgcn_mfma_f32_16x16x32_f16(a0, w1, x1, 0, 0, 0);
    x1 = __builtin_amdgcn_mfma_f32_16x16x32_f16(a1, w0, x1, 0, 0, 0);
}
__device__ __forceinline__ void rwrite1(float* arena, int wave, int lane,
        f32x4 c0, f32x4 c1, f32x4 h0, f32x4 h1) {
    float* b = arena + wave * AST;
    #pragma unroll
    for (int r = 0; r < 4; ++r) {
        b[lane * 4 + r]       = c0[r] + c1[r] * INVS;
        b[256 + lane * 4 + r] = h0[r] + h1[r] * INVS;
    }
}
__device__ __forceinline__ void rsum1(const float* arena, int idx, float& cs, float& hs) {
    float c = 0.f, h = 0.f;
    #pragma unroll
    for (int w = 0; w < 16; ++w) {
        c += arena[w * AST + idx];
        h += arena[w * AST + 256 + idx];
    }
    cs = c; hs = h;
}
__device__ __forceinline__ void fstore(char* fa, int offp, float v) {
    _Float16 u0, u1; limbs2(v, u0, u1);
    unsigned pk = (unsigned)__builtin_bit_cast(unsigned short, u0) |
                  ((unsigned)__builtin_bit_cast(unsigned short, u1) << 16);
    __hip_atomic_store((unsigned*)(fa + offp), pk, __ATOMIC_RELAXED, __HIP_MEMORY_SCOPE_AGENT);
}
template<int ACQ>
__device__ __forceinline__ void pollw(unsigned* f, unsigned tgt, int lane) {
    unsigned v = __hip_atomic_load(f + lane, __ATOMIC_RELAXED, __HIP_MEMORY_SCOPE_AGENT);
    while (__ballot(v < tgt)) {
        __builtin_amdgcn_s_sleep(4);
        v = __hip_atomic_load(f + lane, __ATOMIC_RELAXED, __HIP_MEMORY_SCOPE_AGENT);
    }
    if (ACQ)
        (void)__hip_atomic_load(f, __ATOMIC_ACQUIRE, __HIP_MEMORY_SCOPE_AGENT);
}
__device__ __forceinline__ void publish(unsigned* slot, unsigned v) {
    __hip_atomic_store(slot, v, __ATOMIC_RELAXED, __HIP_MEMORY_SCOPE_AGENT);
}

// ------------------------------ persistent kernel ----------------------------
struct PK {
    const float* x; const float* hidden;
    const unsigned short* wf;
    char* fa; unsigned* flags; float* out;
};

__global__ __launch_bounds__(1024) void persist(PK p) {
    __shared__ float arena[16 * AST];        // ~33 KB reduce arena (16 waves)

    const int tid = threadIdx.x;
    const int wave = tid >> 6, lane = tid & 63;   // wave 0..15
    const int l15 = lane & 15, lg = lane >> 4;
    const int lane8 = lane * 8, lg8 = lg * 8;
    const int bx = blockIdx.x;
    const int cg = (bx & 7) * 8 + ((bx >> 3) & 7);   // same cg set -> same XCD
    const int rt = bx >> 6;

    const unsigned short* wf0 = p.wf;
    const unsigned short* wfs[8];
    #pragma unroll
    for (int i = 0; i < 8; ++i) wfs[i] = p.wf + 8388608ull + (size_t)i * 4194304ull;

    char* FAH  = p.fa + (size_t)(0 * 4 + rt) * 65536;
    char* FAS0 = p.fa + (size_t)(1 * 4 + rt) * 65536;
    char* FAS1 = p.fa + (size_t)(2 * 4 + rt) * 65536;
    char* FAS2 = p.fa + (size_t)(3 * 4 + rt) * 65536;
    char* FAS3 = p.fa + (size_t)(4 * 4 + rt) * 65536;
    char* FAS5 = p.fa + (size_t)(5 * 4 + rt) * 65536;
    #define FLG(tn) (p.flags + ((tn) * 4 + rt) * 64)

    // load this wave's 2-ks weight frags of one matrix; NT = non-temporal hint
    #define WLOAD(wbuf, wfp, nks, kbase, NT) do { \
        _Pragma("unroll") \
        for (int _i = 0; _i < 2; ++_i) { \
            const int _ks = (kbase) + wave * 2 + _i; \
            const unsigned short* _pc = (wfp) + ((size_t)cg * (nks) + _ks) * 1024 + lane8; \
            const unsigned short* _ph = (wfp) + ((size_t)(cg + 64) * (nks) + _ks) * 1024 + lane8; \
            wbuf[_i][0] = ldw<NT>(_pc); wbuf[_i][1] = ldw<NT>(_pc + 512); \
            wbuf[_i][2] = ldw<NT>(_ph); wbuf[_i][3] = ldw<NT>(_ph + 512); } } while (0)
    #define ALD(dst0, dst1, fa) do { \
        _Pragma("unroll") \
        for (int _i = 0; _i < 2; ++_i) aload(fa, wave * 2 + _i, lane, dst0[_i], dst1[_i]); } while (0)
    #define GEMM(wbuf, A0, A1, X0, X1, Y0, Y1) do { \
        _Pragma("unroll") \
        for (int _i = 0; _i < 2; ++_i) { \
            mfma6(A0[_i], A1[_i], wbuf[_i][0], wbuf[_i][1], X0, X1); \
            mfma6(A0[_i], A1[_i], wbuf[_i][2], wbuf[_i][3], Y0, Y1); } } while (0)

    const int rowf = tid >> 4, colf = tid & 15;            // epilogue pos (tid<256)
    const size_t opos = (size_t)(rt * 16 + rowf) * NH + cg * 16 + colf;
    const int idx = colf * 4 + (rowf >> 2) * 64 + (rowf & 3);
    int offp;
    {
        int col = cg * 16 + colf;
        int ksp = col >> 5, kin = col & 31;
        int lanep = (kin >> 3) * 16 + rowf;
        offp = (ksp * 64 + lanep) * 32 + (kin & 7) * 4;
    }
    float hprev = 0.f, s0v = 0.f, s1v = 0.f, s2v = 0.f, s3v = 0.f, s5v = 0.f, runsum = 0.f;
    if (tid < 256) hprev = p.hidden[opos];
    const int xrow = rt * 16 + l15;
    __syncthreads();

    for (int t = 0; t < T_STEPS; ++t) {
        const float* xt = p.x + (size_t)t * 65536;
        half8 a0[2], a1[2];

        // ===== L1: x-part pre-poll (h-independent); h-part post-acquire ======
        f32x4 c0 = {}, c1 = {}, h0 = {}, h1 = {};
        {
            half8 wx[2][4], xa0[2], xa1[2];
            WLOAD(wx, wf0, 64, 0, 1);                    // W0 x-rows (nt)
            #pragma unroll
            for (int i = 0; i < 2; ++i) {
                const int ks = wave * 2 + i;
                const float* xp = xt + (size_t)xrow * NH + ks * 32 + lg8;
                float4 v0 = *(const float4*)xp, v1 = *(const float4*)(xp + 4);
                float fv[8] = {v0.x, v0.y, v0.z, v0.w, v1.x, v1.y, v1.z, v1.w};
                #pragma unroll
                for (int j = 0; j < 8; ++j) { _Float16 u, w2; limbs2(fv[j], u, w2); xa0[i][j] = u; xa1[i][j] = w2; }
            }
            GEMM(wx, xa0, xa1, c0, c1, h0, h1);
            half8 wh[2][4];
            WLOAD(wh, wf0, 64, 32, 1);                   // W0 h-rows (nt, pre-poll)
            if (wave == 15) pollw<1>(FLG(0), t + 1, lane);   // the step's ONE acquire
            __syncthreads();
            half8 ha0[2], ha1[2];
            ALD(ha0, ha1, FAH);
            GEMM(wh, ha0, ha1, c0, c1, h0, h1);
            rwrite1(arena, wave, lane, c0, c1, h0, h1);
        }
        LBAR();
        if (tid < 256) {
            float cs, hs; rsum1(arena, idx, cs, hs);
            s0v = hprev + sigf(cs) * (tanhf(hs) - hprev);
            fstore(FAS0, offp, s0v);
        }
        __syncthreads();
        if (tid == 0) publish(FLG(1) + cg, t + 1);

        // ===== L2: s1 = comb(s0, s0 @ Ws0)  (Ws0 L2-resident) ================
        {
            half8 w0[2][4];
            WLOAD(w0, wfs[0], 32, 0, 0);
            pollw<0>(FLG(1), t + 1, lane);               // all waves, no barrier
            ALD(a0, a1, FAS0);
            f32x4 X0 = {}, X1 = {}, Y0 = {}, Y1 = {};
            GEMM(w0, a0, a1, X0, X1, Y0, Y1);
            rwrite1(arena, wave, lane, X0, X1, Y0, Y1);
        }
        LBAR();
        if (tid < 256) {
            float cs, hs; rsum1(arena, idx, cs, hs);
            s1v = s0v + sigf(cs) * (sigf(hs) - s0v);
            fstore(FAS1, offp, s1v);
            runsum = s1v;
        }
        __syncthreads();
        if (tid == 0) publish(FLG(2) + cg, t + 1);

        // ===== L3: s2,s3,s4 from s1 (Ws1,Ws2 resident; Ws3 nt) ===============
        {
            half8 w1[2][4], w2[2][4];
            WLOAD(w1, wfs[1], 32, 0, 0);
            WLOAD(w2, wfs[2], 32, 0, 0);
            pollw<0>(FLG(2), t + 1, lane);               // all waves, no barrier
            ALD(a0, a1, FAS1);
            f32x4 X0 = {}, X1 = {}, Y0 = {}, Y1 = {};
            GEMM(w1, a0, a1, X0, X1, Y0, Y1);
            half8 w3[2][4];
            WLOAD(w3, wfs[3], 32, 0, 1);
            rwrite1(arena, wave, lane, X0, X1, Y0, Y1);
            LBAR();
            if (tid < 256) {
                float cs, hs; rsum1(arena, idx, cs, hs);
                s2v = s1v + sigf(cs) * (fmaxf(hs, 0.f) - s1v);
                fstore(FAS2, offp, s2v);
            }
            __syncthreads();
            if (tid == 0) publish(FLG(3) + cg, t + 1);
            X0 = (f32x4){}; X1 = (f32x4){}; Y0 = (f32x4){}; Y1 = (f32x4){};
            GEMM(w2, a0, a1, X0, X1, Y0, Y1);
            rwrite1(arena, wave, lane, X0, X1, Y0, Y1);
            LBAR();
            if (tid < 256) {
                float cs, hs; rsum1(arena, idx, cs, hs);
                s3v = s1v + sigf(cs) * (fmaxf(hs, 0.f) - s1v);
                fstore(FAS3, offp, s3v);
            }
            __syncthreads();
            if (tid == 0) publish(FLG(4) + cg, t + 1);
            X0 = (f32x4){}; X1 = (f32x4){}; Y0 = (f32x4){}; Y1 = (f32x4){};
            GEMM(w3, a0, a1, X0, X1, Y0, Y1);
            rwrite1(arena, wave, lane, X0, X1, Y0, Y1);
            LBAR();
            if (tid < 256) {
                float cs, hs; rsum1(arena, idx, cs, hs);
                float s4v = s1v + sigf(cs) * (hs - s1v);
                runsum += s2v + s3v + s4v;
            }
            LBAR();                                      // arena safe before L4
        }

        // ===== L4: s5 = comb(s2,Ws4), s7 = comb(s3,Ws6)  (nt) ================
        {
            half8 w4[2][4], w6[2][4];
            WLOAD(w4, wfs[4], 32, 0, 1);
            WLOAD(w6, wfs[6], 32, 0, 1);
            pollw<0>(FLG(3), t + 1, lane);               // all waves
            pollw<0>(FLG(4), t + 1, lane);
            half8 b0[2], b1[2];
            ALD(a0, a1, FAS2);
            ALD(b0, b1, FAS3);
            f32x4 X0 = {}, X1 = {}, Y0 = {}, Y1 = {};
            GEMM(w4, a0, a1, X0, X1, Y0, Y1);
            f32x4 U0 = {}, U1 = {}, V0 = {}, V1 = {};
            GEMM(w6, b0, b1, U0, U1, V0, V1);
            rwrite1(arena, wave, lane, X0, X1, Y0, Y1);
            LBAR();
            if (tid < 256) {
                float cs, hs; rsum1(arena, idx, cs, hs);
                s5v = s2v + sigf(cs) * (tanhf(hs) - s2v);
                fstore(FAS5, offp, s5v);
            }
            __syncthreads();
            if (tid == 0) publish(FLG(5) + cg, t + 1);
            rwrite1(arena, wave, lane, U0, U1, V0, V1);
            LBAR();
            if (tid < 256) {
                float cs, hs; rsum1(arena, idx, cs, hs);
                float s7v = s3v + sigf(cs) * (tanhf(hs) - s3v);
                runsum += s5v + s7v;
            }
            LBAR();                                      // arena safe before L5
        }

        // ===== L5: s6,s8 from s5 + mean -> out[t], publish H  (nt) ===========
        {
            half8 w5[2][4], w7[2][4];
            WLOAD(w5, wfs[5], 32, 0, 1);
            WLOAD(w7, wfs[7], 32, 0, 1);
            pollw<0>(FLG(5), t + 1, lane);               // all waves
            ALD(a0, a1, FAS5);
            f32x4 X0 = {}, X1 = {}, Y0 = {}, Y1 = {};
            GEMM(w5, a0, a1, X0, X1, Y0, Y1);
            f32x4 U0 = {}, U1 = {}, V0 = {}, V1 = {};
            GEMM(w7, a0, a1, U0, U1, V0, V1);
            rwrite1(arena, wave, lane, X0, X1, Y0, Y1);
            LBAR();
            float c6 = 0.f, h6 = 0.f;
            if (tid < 256) rsum1(arena, idx, c6, h6);
            LBAR();                                      // readers done before rewrite
            rwrite1(arena, wave, lane, U0, U1, V0, V1);
            LBAR();
            if (tid < 256) {
                float c8, h8; rsum1(arena, idx, c8, h8);
                float s6 = s5v + sigf(c6) * (sigf(h6) - s5v);
                float s8 = s5v + sigf(c8) * (fmaxf(h8, 0.f) - s5v);
                float v = 0.125f * (runsum + s6 + s8);
                p.out[(size_t)t * 65536 + opos] = v;
                fstore(FAH, offp, v);
                hprev = v;
            }
            __syncthreads();
            if (tid == 0) publish(FLG(0) + cg, t + 2);
        }
    }
    #undef FLG
    #undef WLOAD
    #undef ALD
    #undef GEMM
}

// ---------------------------------- host -------------------------------------
extern "C" void kernel_launch(void* const* d_in, const int* in_sizes, int n_in,
                              void* d_out, int out_size, void* d_ws, size_t ws_size,
                              hipStream_t stream) {
    (void)in_sizes; (void)n_in; (void)out_size; (void)ws_size;
    const float* inputs = (const float*)d_in[0];
    const float* hidden = (const float*)d_in[1];
    const float* W0     = (const float*)d_in[2];
    const float* Ws     = (const float*)d_in[3];
    float* out = (float*)d_out;

    char* base = (char*)d_ws;
    unsigned short* wf = (unsigned short*)base;
    char* fa = base + WF_BYTES;
    unsigned* flags = (unsigned*)(fa + FA_BYTES);

    initk<<<64, 256, 0, stream>>>(hidden, fa, flags);
    preconv<<<10240, 256, 0, stream>>>(Pre{W0, Ws, wf});

    PK pk{inputs, hidden, wf, fa, flags, out};
    void* args[] = {&pk};
    if (hipLaunchCooperativeKernel((void*)persist, dim3(256), dim3(1024), args, 0, stream) != hipSuccess)
        persist<<<256, 1024, 0, stream>>>(pk);
}

// Round 12
// 12647.383 us; speedup vs baseline: 1.0377x; 1.0377x over previous
//
#include <hip/hip_runtime.h>
#include <math.h>

// DARTS recurrent cell on MI355X — persistent cooperative kernel, v12.
// v12 = exact v7 structure (best measured: 9.71 ms; pre-poll weight issue,
// one acquire/step, W0h LDS slab) + quad epilogue:
//  - reduction read as contiguous f32x4 per thread (b128, conflict-free)
//    by 64 threads each owning 4 outputs, replacing 256-thread stride-4
//    scalar reads (8-way bank conflict, the 7.55e7 counter).
// nt hints and per-wave polling (v11) reverted — both proven regressions.

typedef __attribute__((ext_vector_type(8))) _Float16 half8;
typedef __attribute__((ext_vector_type(4))) float f32x4;
typedef __attribute__((ext_vector_type(4))) unsigned int u32x4;
typedef __attribute__((ext_vector_type(8))) unsigned short us8;

#define NH 1024
#define SCALE 2048.f
#define INVS  (1.f/2048.f)
#define WF_BYTES 83886080ull
#define FA_BYTES 1572864ull
#define T_STEPS  256

#define LBAR() asm volatile("s_waitcnt lgkmcnt(0)\n\ts_barrier" ::: "memory")

__device__ __forceinline__ float sigf(float x){ return 1.f/(1.f+__expf(-x)); }
__device__ __forceinline__ void limbs2(float x, _Float16& a, _Float16& b){
    a = (_Float16)x; b = (_Float16)((x - (float)a)*SCALE);
}

// ---------------- weight pre-swizzle (identical to v4-v11, proven) -----------
struct Pre { const float* W0; const float* Ws; unsigned short* wf; };

__global__ __launch_bounds__(256) void preconv(Pre d) {
    int gid  = blockIdx.x * 4 + (threadIdx.x >> 6);
    int lane = threadIdx.x & 63;
    const float* W; unsigned short* dst; int nks, cg, ks;
    if (gid < 8192) {
        W = d.W0; dst = d.wf; nks = 64; cg = gid >> 6; ks = gid & 63;
    } else {
        int g = gid - 8192; int mm = g >> 12; int wi = g & 4095;
        W   = d.Ws + (size_t)mm * (1024 * 2048);
        dst = d.wf + 8388608ull + (size_t)mm * 4194304ull;
        nks = 32; cg = wi >> 5; ks = wi & 31;
    }
    int c  = cg * 16 + (lane & 15);
    int kb = ks * 32 + (lane >> 4) * 8;
    half8 h0, h1;
    #pragma unroll
    for (int j = 0; j < 8; ++j) {
        _Float16 p, q; limbs2(W[(size_t)(kb + j) * 2048 + c], p, q);
        h0[j] = p; h1[j] = q;
    }
    unsigned short* o = dst + ((size_t)cg * nks + ks) * 1024 + lane * 8;
    *(half8*)o         = h0;
    *(half8*)(o + 512) = h1;
}

// -------- init: hidden -> interleaved H frag plane; flag init ----------------
__global__ __launch_bounds__(256) void initk(const float* hidden, char* fa, unsigned* flags) {
    int gid = blockIdx.x * 256 + threadIdx.x;
    if (gid < 1536) flags[gid] = (gid < 256) ? 1u : 0u;
    #pragma unroll
    for (int e = 0; e < 4; ++e) {
        int i = gid * 4 + e;
        int row = i >> 10, col = i & 1023;
        int rt = row >> 4, rowf = row & 15;
        int ksp = col >> 5, kin = col & 31;
        int lanep = (kin >> 3) * 16 + rowf;
        size_t off = (size_t)rt * 65536 + ((size_t)ksp * 64 + lanep) * 32 + (kin & 7) * 4;
        _Float16 u0, u1; limbs2(hidden[i], u0, u1);
        unsigned pk = (unsigned)__builtin_bit_cast(unsigned short, u0) |
                      ((unsigned)__builtin_bit_cast(unsigned short, u1) << 16);
        *(unsigned*)(fa + off) = pk;
    }
}

// ------------------------------ device helpers -------------------------------
__device__ __forceinline__ void aload(const char* fa, int ks, int lane, half8& a0, half8& a1) {
    const char* p = fa + ((size_t)ks * 64 + lane) * 32;
    us8 q0 = *(const us8*)p;
    us8 q1 = *(const us8*)(p + 16);
    a0 = __builtin_bit_cast(half8, __builtin_shufflevector(q0, q1, 0,2,4,6,8,10,12,14));
    a1 = __builtin_bit_cast(half8, __builtin_shufflevector(q0, q1, 1,3,5,7,9,11,13,15));
}
__device__ __forceinline__ half8 ldw(const unsigned short* p) { return *(const half8*)p; }
__device__ __forceinline__ void mfma6(half8 a0, half8 a1, half8 w0, half8 w1,
                                      f32x4& x0, f32x4& x1) {
    x0 = __builtin_amdgcn_mfma_f32_16x16x32_f16(a0, w0, x0, 0, 0, 0);
    x1 = __builtin_amdgcn_mfma_f32_16x16x32_f16(a0, w1, x1, 0, 0, 0);
    x1 = __builtin_amdgcn_mfma_f32_16x16x32_f16(a1, w0, x1, 0, 0, 0);
}
__device__ __forceinline__ void rwrite1(float* arena, int wave, int lane,
        f32x4 c0, f32x4 c1, f32x4 h0, f32x4 h1) {
    float* b = arena + wave * 512;
    f32x4 cv, hv;
    #pragma unroll
    for (int r = 0; r < 4; ++r) { cv[r] = c0[r] + c1[r] * INVS; hv[r] = h0[r] + h1[r] * INVS; }
    *(f32x4*)(b + lane * 4)       = cv;     // contiguous 16B/lane: conflict-free
    *(f32x4*)(b + 256 + lane * 4) = hv;
}
// quad reduction: thread e reads contiguous f32x4 per wave section (b128).
// word lane*4+r holds (col=lane&15, row=(lane>>4)*4+r) -> thread e owns
// col=e&15, rows (e>>4)*4..+3.
__device__ __forceinline__ void rsumq(const float* arena, int e, f32x4& cs, f32x4& hs) {
    f32x4 c = {}, h = {};
    #pragma unroll
    for (int w = 0; w < 8; ++w) {
        c += *(const f32x4*)(arena + w * 512 + e * 4);
        h += *(const f32x4*)(arena + w * 512 + 256 + e * 4);
    }
    cs = c; hs = h;
}
__device__ __forceinline__ void fstore(char* fa, int offp, float v) {
    _Float16 u0, u1; limbs2(v, u0, u1);
    unsigned pk = (unsigned)__builtin_bit_cast(unsigned short, u0) |
                  ((unsigned)__builtin_bit_cast(unsigned short, u1) << 16);
    __hip_atomic_store((unsigned*)(fa + offp), pk, __ATOMIC_RELAXED, __HIP_MEMORY_SCOPE_AGENT);
}
template<int ACQ>
__device__ __forceinline__ void pollw(unsigned* f, unsigned tgt, int lane) {
    unsigned v = __hip_atomic_load(f + lane, __ATOMIC_RELAXED, __HIP_MEMORY_SCOPE_AGENT);
    while (__ballot(v < tgt)) {
        __builtin_amdgcn_s_sleep(2);
        v = __hip_atomic_load(f + lane, __ATOMIC_RELAXED, __HIP_MEMORY_SCOPE_AGENT);
    }
    if (ACQ)
        (void)__hip_atomic_load(f, __ATOMIC_ACQUIRE, __HIP_MEMORY_SCOPE_AGENT);
}
__device__ __forceinline__ void publish(unsigned* slot, unsigned v) {
    __hip_atomic_store(slot, v, __ATOMIC_RELAXED, __HIP_MEMORY_SCOPE_AGENT);
}

// ------------------------------ persistent kernel ----------------------------
struct PK {
    const float* x; const float* hidden;
    const unsigned short* wf;
    char* fa; unsigned* flags; float* out;
};

__global__ __launch_bounds__(512, 2) void persist(PK p) {
    __shared__ unsigned short slab[65536];   // 128 KB: W0h frags
    __shared__ float arena[4096];            // 16 KB reduce arena

    const int tid  = threadIdx.x;
    const int wave = tid >> 6, lane = tid & 63;
    const int l15 = lane & 15, lg = lane >> 4;
    const int lane8 = lane * 8, lg8 = lg * 8;
    const int bx = blockIdx.x;
    const int cg = (bx & 7) * 8 + ((bx >> 3) & 7);
    const int rt = bx >> 6;

    const unsigned short* wf0 = p.wf;
    const unsigned short* wfs[8];
    #pragma unroll
    for (int i = 0; i < 8; ++i) wfs[i] = p.wf + 8388608ull + (size_t)i * 4194304ull;

    char* FAH  = p.fa + (size_t)(0 * 4 + rt) * 65536;
    char* FAS0 = p.fa + (size_t)(1 * 4 + rt) * 65536;
    char* FAS1 = p.fa + (size_t)(2 * 4 + rt) * 65536;
    char* FAS2 = p.fa + (size_t)(3 * 4 + rt) * 65536;
    char* FAS3 = p.fa + (size_t)(4 * 4 + rt) * 65536;
    char* FAS5 = p.fa + (size_t)(5 * 4 + rt) * 65536;
    #define FLG(tn) (p.flags + ((tn) * 4 + rt) * 64)

    #define PFW(dst, wfp) do { \
        _Pragma("unroll") \
        for (int _i = 0; _i < 4; ++_i) { \
            const int _ks = wave * 4 + _i; \
            const unsigned short* _pc = (wfp) + ((size_t)cg * 32 + _ks) * 1024 + lane8; \
            const unsigned short* _ph = (wfp) + ((size_t)(cg + 64) * 32 + _ks) * 1024 + lane8; \
            dst[_i*4+0] = ldw(_pc); dst[_i*4+1] = ldw(_pc + 512); \
            dst[_i*4+2] = ldw(_ph); dst[_i*4+3] = ldw(_ph + 512); } } while (0)
    #define ALD(dst0, dst1, fa) do { \
        _Pragma("unroll") \
        for (int _i = 0; _i < 4; ++_i) aload(fa, wave * 4 + _i, lane, dst0[_i], dst1[_i]); } while (0)
    #define MFM(w, a0v, a1v, X0, X1, Y0, Y1) do { \
        _Pragma("unroll") \
        for (int _i = 0; _i < 4; ++_i) { \
            mfma6(a0v[_i], a1v[_i], w[_i*4+0], w[_i*4+1], X0, X1); \
            mfma6(a0v[_i], a1v[_i], w[_i*4+2], w[_i*4+3], Y0, Y1); } } while (0)

    // ---- fill W0h LDS slab (once) ----
    {
        const u32x4* sc = (const u32x4*)(wf0 + ((size_t)cg * 64 + 32) * 1024);
        const u32x4* sh = (const u32x4*)(wf0 + ((size_t)(cg + 64) * 64 + 32) * 1024);
        u32x4* dst = (u32x4*)slab;
        for (int i = tid; i < 4096; i += 512) { dst[i] = sc[i]; dst[4096 + i] = sh[i]; }
    }

    // quad-epilogue fixed positions (tid < 64): col = tid&15, rows (tid>>4)*4..+3
    size_t opos[4] = {0, 0, 0, 0};
    int offp[4] = {0, 0, 0, 0};
    float hprev[4] = {}, s0v[4] = {}, s1v[4] = {}, s2v[4] = {}, s3v[4] = {}, s5v[4] = {}, runsum[4] = {};
    if (tid < 64) {
        const int colf = tid & 15, rq = (tid >> 4) * 4;
        const int col = cg * 16 + colf;
        const int ksp = col >> 5, kin = col & 31;
        #pragma unroll
        for (int r = 0; r < 4; ++r) {
            const int rowf = rq + r;
            opos[r] = (size_t)(rt * 16 + rowf) * NH + col;
            offp[r] = (ksp * 64 + (kin >> 3) * 16 + rowf) * 32 + (kin & 7) * 4;
            hprev[r] = p.hidden[opos[r]];
        }
    }
    const int xrow = rt * 16 + l15;
    __syncthreads();

    for (int t = 0; t < T_STEPS; ++t) {
        const float* xt = p.x + (size_t)t * 65536;

        // ========== L1: x-part first (h-independent), poll hidden under it ===
        f32x4 c0 = {}, c1 = {}, h0 = {}, h1 = {};
        {
            half8 xw[16], xa0[4], xa1[4];
            #pragma unroll
            for (int i = 0; i < 4; ++i) {           // prefetch W0x + load x
                const int ks = wave * 4 + i;
                const unsigned short* pc = wf0 + ((size_t)cg * 64 + ks) * 1024 + lane8;
                const unsigned short* ph = wf0 + ((size_t)(cg + 64) * 64 + ks) * 1024 + lane8;
                xw[i*4+0] = ldw(pc); xw[i*4+1] = ldw(pc + 512);
                xw[i*4+2] = ldw(ph); xw[i*4+3] = ldw(ph + 512);
                const float* xp = xt + (size_t)xrow * NH + ks * 32 + lg8;
                float4 v0 = *(const float4*)xp, v1 = *(const float4*)(xp + 4);
                float fv[8] = {v0.x, v0.y, v0.z, v0.w, v1.x, v1.y, v1.z, v1.w};
                #pragma unroll
                for (int j = 0; j < 8; ++j) { _Float16 u, w2; limbs2(fv[j], u, w2); xa0[i][j] = u; xa1[i][j] = w2; }
            }
            if (wave == 7) pollw<1>(FLG(0), t + 1, lane);     // the step's ONE acquire
            MFM(xw, xa0, xa1, c0, c1, h0, h1);
        }
        __syncthreads();                            // acquire ordered before FAH reads
        {
            half8 ha0[4], ha1[4];
            ALD(ha0, ha1, FAH);
            #pragma unroll
            for (int i = 0; i < 4; ++i) {           // W0h from LDS slab
                const int kc = wave * 4 + i;
                const unsigned short* pc = &slab[kc * 1024 + lane8];
                const unsigned short* ph = &slab[(kc + 32) * 1024 + lane8];
                mfma6(ha0[i], ha1[i], *(const half8*)pc, *(const half8*)(pc + 512), c0, c1);
                mfma6(ha0[i], ha1[i], *(const half8*)ph, *(const half8*)(ph + 512), h0, h1);
            }
            rwrite1(arena, wave, lane, c0, c1, h0, h1);
        }
        LBAR();
        if (tid < 64) {
            f32x4 cs, hs; rsumq(arena, tid, cs, hs);
            #pragma unroll
            for (int r = 0; r < 4; ++r) {
                s0v[r] = hprev[r] + sigf(cs[r]) * (tanhf(hs[r]) - hprev[r]);
                fstore(FAS0, offp[r], s0v[r]);
            }
        }
        __syncthreads();
        if (tid == 0) publish(FLG(1) + cg, t + 1);

        // ========== L2: s1 = comb(s0, s0 @ Ws0)  (Ws0 prefetched pre-poll) ===
        {
            half8 w0[16];
            PFW(w0, wfs[0]);
            if (wave == 7) pollw<0>(FLG(1), t + 1, lane);
            __syncthreads();
            half8 a0[4], a1[4];
            ALD(a0, a1, FAS0);
            f32x4 X0 = {}, X1 = {}, Y0 = {}, Y1 = {};
            MFM(w0, a0, a1, X0, X1, Y0, Y1);
            rwrite1(arena, wave, lane, X0, X1, Y0, Y1);
        }
        LBAR();
        if (tid < 64) {
            f32x4 cs, hs; rsumq(arena, tid, cs, hs);
            #pragma unroll
            for (int r = 0; r < 4; ++r) {
                s1v[r] = s0v[r] + sigf(cs[r]) * (sigf(hs[r]) - s0v[r]);
                fstore(FAS1, offp[r], s1v[r]);
                runsum[r] = s1v[r];
            }
        }
        __syncthreads();
        if (tid == 0) publish(FLG(2) + cg, t + 1);

        // ========== L3: s2,s3,s4 (Ws1+Ws2 pre-poll; Ws3 under Ws1 MFMAs) =====
        {
            half8 w1[16], w2[16];
            PFW(w1, wfs[1]);
            PFW(w2, wfs[2]);
            if (wave == 7) pollw<0>(FLG(2), t + 1, lane);
            __syncthreads();
            half8 a0[4], a1[4];
            ALD(a0, a1, FAS1);
            f32x4 X0 = {}, X1 = {}, Y0 = {}, Y1 = {};
            MFM(w1, a0, a1, X0, X1, Y0, Y1);
            half8 w3[16];
            PFW(w3, wfs[3]);                        // issue under the arena dance
            rwrite1(arena, wave, lane, X0, X1, Y0, Y1);
            LBAR();
            if (tid < 64) {
                f32x4 cs, hs; rsumq(arena, tid, cs, hs);
                #pragma unroll
                for (int r = 0; r < 4; ++r) {
                    s2v[r] = s1v[r] + sigf(cs[r]) * (fmaxf(hs[r], 0.f) - s1v[r]);
                    fstore(FAS2, offp[r], s2v[r]);
                }
            }
            __syncthreads();
            if (tid == 0) publish(FLG(3) + cg, t + 1);
            X0 = (f32x4){}; X1 = (f32x4){}; Y0 = (f32x4){}; Y1 = (f32x4){};
            MFM(w2, a0, a1, X0, X1, Y0, Y1);
            rwrite1(arena, wave, lane, X0, X1, Y0, Y1);
            LBAR();
            if (tid < 64) {
                f32x4 cs, hs; rsumq(arena, tid, cs, hs);
                #pragma unroll
                for (int r = 0; r < 4; ++r) {
                    s3v[r] = s1v[r] + sigf(cs[r]) * (fmaxf(hs[r], 0.f) - s1v[r]);
                    fstore(FAS3, offp[r], s3v[r]);
                }
            }
            __syncthreads();
            if (tid == 0) publish(FLG(4) + cg, t + 1);
            X0 = (f32x4){}; X1 = (f32x4){}; Y0 = (f32x4){}; Y1 = (f32x4){};
            MFM(w3, a0, a1, X0, X1, Y0, Y1);
            rwrite1(arena, wave, lane, X0, X1, Y0, Y1);
            LBAR();
            if (tid < 64) {
                f32x4 cs, hs; rsumq(arena, tid, cs, hs);
                #pragma unroll
                for (int r = 0; r < 4; ++r) {
                    float s4 = s1v[r] + sigf(cs[r]) * (hs[r] - s1v[r]);
                    runsum[r] += s2v[r] + s3v[r] + s4;
                }
            }
            __syncthreads();
        }

        // ========== L4: s5 (Ws4, A=s2), s7 (Ws6, A=s3)  (both pre-poll) ======
        {
            half8 w4[16], w6[16];
            PFW(w4, wfs[4]);
            PFW(w6, wfs[6]);
            if (wave == 7) { pollw<0>(FLG(3), t + 1, lane); pollw<0>(FLG(4), t + 1, lane); }
            __syncthreads();
            half8 a0[4], a1[4], b0[4], b1[4];
            ALD(a0, a1, FAS2);
            ALD(b0, b1, FAS3);
            f32x4 X0 = {}, X1 = {}, Y0 = {}, Y1 = {};
            MFM(w4, a0, a1, X0, X1, Y0, Y1);
            f32x4 U0 = {}, U1 = {}, V0 = {}, V1 = {};
            MFM(w6, b0, b1, U0, U1, V0, V1);
            rwrite1(arena, wave, lane, X0, X1, Y0, Y1);
            LBAR();
            if (tid < 64) {
                f32x4 cs, hs; rsumq(arena, tid, cs, hs);
                #pragma unroll
                for (int r = 0; r < 4; ++r) {
                    s5v[r] = s2v[r] + sigf(cs[r]) * (tanhf(hs[r]) - s2v[r]);
                    fstore(FAS5, offp[r], s5v[r]);
                }
            }
            __syncthreads();
            if (tid == 0) publish(FLG(5) + cg, t + 1);
            rwrite1(arena, wave, lane, U0, U1, V0, V1);
            LBAR();
            if (tid < 64) {
                f32x4 cs, hs; rsumq(arena, tid, cs, hs);
                #pragma unroll
                for (int r = 0; r < 4; ++r) {
                    float s7 = s3v[r] + sigf(cs[r]) * (tanhf(hs[r]) - s3v[r]);
                    runsum[r] += s5v[r] + s7;
                }
            }
            __syncthreads();
            PFW(w4, wfs[5]);                        // reuse regs: Ws5 -> L5
        }

        // ========== L5: s6,s8 (Ws5,Ws7, A=s5) + mean -> out[t] ===============
        {
            half8 w5[16], w7[16];
            PFW(w5, wfs[5]);
            PFW(w7, wfs[7]);
            if (wave == 7) pollw<0>(FLG(5), t + 1, lane);
            __syncthreads();
            half8 a0[4], a1[4];
            ALD(a0, a1, FAS5);
            f32x4 X0 = {}, X1 = {}, Y0 = {}, Y1 = {};
            MFM(w5, a0, a1, X0, X1, Y0, Y1);
            f32x4 U0 = {}, U1 = {}, V0 = {}, V1 = {};
            MFM(w7, a0, a1, U0, U1, V0, V1);
            rwrite1(arena, wave, lane, X0, X1, Y0, Y1);
            LBAR();
            f32x4 c6 = {}, h6 = {};
            if (tid < 64) rsumq(arena, tid, c6, h6);
            LBAR();                                 // readers done before rewrite
            rwrite1(arena, wave, lane, U0, U1, V0, V1);
            LBAR();
            if (tid < 64) {
                f32x4 c8, h8; rsumq(arena, tid, c8, h8);
                #pragma unroll
                for (int r = 0; r < 4; ++r) {
                    float s6 = s5v[r] + sigf(c6[r]) * (sigf(h6[r]) - s5v[r]);
                    float s8 = s5v[r] + sigf(c8[r]) * (fmaxf(h8[r], 0.f) - s5v[r]);
                    float v = 0.125f * (runsum[r] + s6 + s8);
                    p.out[(size_t)t * 65536 + opos[r]] = v;
                    fstore(FAH, offp[r], v);
                    hprev[r] = v;
                }
            }
            __syncthreads();
            if (tid == 0) publish(FLG(0) + cg, t + 2);
        }
    }
    #undef FLG
    #undef PFW
    #undef ALD
    #undef MFM
}

// ---------------------------------- host -------------------------------------
extern "C" void kernel_launch(void* const* d_in, const int* in_sizes, int n_in,
                              void* d_out, int out_size, void* d_ws, size_t ws_size,
                              hipStream_t stream) {
    (void)in_sizes; (void)n_in; (void)out_size; (void)ws_size;
    const float* inputs = (const float*)d_in[0];
    const float* hidden = (const float*)d_in[1];
    const float* W0     = (const float*)d_in[2];
    const float* Ws     = (const float*)d_in[3];
    float* out = (float*)d_out;

    char* base = (char*)d_ws;
    unsigned short* wf = (unsigned short*)base;
    char* fa = base + WF_BYTES;
    unsigned* flags = (unsigned*)(fa + FA_BYTES);

    initk<<<64, 256, 0, stream>>>(hidden, fa, flags);
    preconv<<<10240, 256, 0, stream>>>(Pre{W0, Ws, wf});

    PK pk{inputs, hidden, wf, fa, flags, out};
    void* args[] = {&pk};
    if (hipLaunchCooperativeKernel((void*)persist, dim3(256), dim3(512), args, 0, stream) != hipSuccess)
        persist<<<256, 512, 0, stream>>>(pk);
}

// Round 13
// 9553.952 us; speedup vs baseline: 1.3736x; 1.3238x over previous
//
#include <hip/hip_runtime.h>
#include <math.h>

// DARTS recurrent cell on MI355X — persistent cooperative kernel, v13.
// v13 = exact v7 (best measured, 9.71 ms) + hoisted x@W0x precompute:
//  - xw0_gemm computes XC/XH[t][64][1024] fp32 for all t once (256 WGs loop
//    over t; W0x frags L2-resident after t=0). Persist L1 drops the x-path
//    (8.4 MB/step W0x stream + x reads + conversions), adds 2 scalar loads.
//  - v12's quad epilogue reverted (WRITE_SIZE 7x blowup: scattered stores).
//  - fallback (ws too small): exact v7 path (XPRE=0).

typedef __attribute__((ext_vector_type(8))) _Float16 half8;
typedef __attribute__((ext_vector_type(4))) float f32x4;
typedef __attribute__((ext_vector_type(4))) unsigned int u32x4;
typedef __attribute__((ext_vector_type(8))) unsigned short us8;

#define NH 1024
#define SCALE 2048.f
#define INVS  (1.f/2048.f)
#define WF_BYTES 83886080ull
#define FA_BYTES 1572864ull
#define XW_BYTES 134217728ull
#define T_STEPS  256

#define LBAR() asm volatile("s_waitcnt lgkmcnt(0)\n\ts_barrier" ::: "memory")

__device__ __forceinline__ float sigf(float x){ return 1.f/(1.f+__expf(-x)); }
__device__ __forceinline__ void limbs2(float x, _Float16& a, _Float16& b){
    a = (_Float16)x; b = (_Float16)((x - (float)a)*SCALE);
}

// ---------------- weight pre-swizzle (identical to v4-v12, proven) -----------
struct Pre { const float* W0; const float* Ws; unsigned short* wf; };

__global__ __launch_bounds__(256) void preconv(Pre d) {
    int gid  = blockIdx.x * 4 + (threadIdx.x >> 6);
    int lane = threadIdx.x & 63;
    const float* W; unsigned short* dst; int nks, cg, ks;
    if (gid < 8192) {
        W = d.W0; dst = d.wf; nks = 64; cg = gid >> 6; ks = gid & 63;
    } else {
        int g = gid - 8192; int mm = g >> 12; int wi = g & 4095;
        W   = d.Ws + (size_t)mm * (1024 * 2048);
        dst = d.wf + 8388608ull + (size_t)mm * 4194304ull;
        nks = 32; cg = wi >> 5; ks = wi & 31;
    }
    int c  = cg * 16 + (lane & 15);
    int kb = ks * 32 + (lane >> 4) * 8;
    half8 h0, h1;
    #pragma unroll
    for (int j = 0; j < 8; ++j) {
        _Float16 p, q; limbs2(W[(size_t)(kb + j) * 2048 + c], p, q);
        h0[j] = p; h1[j] = q;
    }
    unsigned short* o = dst + ((size_t)cg * nks + ks) * 1024 + lane * 8;
    *(half8*)o         = h0;
    *(half8*)(o + 512) = h1;
}

// -------- init: hidden -> interleaved H frag plane; flag init ----------------
__global__ __launch_bounds__(256) void initk(const float* hidden, char* fa, unsigned* flags) {
    int gid = blockIdx.x * 256 + threadIdx.x;
    if (gid < 1536) flags[gid] = (gid < 256) ? 1u : 0u;
    #pragma unroll
    for (int e = 0; e < 4; ++e) {
        int i = gid * 4 + e;
        int row = i >> 10, col = i & 1023;
        int rt = row >> 4, rowf = row & 15;
        int ksp = col >> 5, kin = col & 31;
        int lanep = (kin >> 3) * 16 + rowf;
        size_t off = (size_t)rt * 65536 + ((size_t)ksp * 64 + lanep) * 32 + (kin & 7) * 4;
        _Float16 u0, u1; limbs2(hidden[i], u0, u1);
        unsigned pk = (unsigned)__builtin_bit_cast(unsigned short, u0) |
                      ((unsigned)__builtin_bit_cast(unsigned short, u1) << 16);
        *(unsigned*)(fa + off) = pk;
    }
}

// ------------------------------ device helpers -------------------------------
__device__ __forceinline__ void aload(const char* fa, int ks, int lane, half8& a0, half8& a1) {
    const char* p = fa + ((size_t)ks * 64 + lane) * 32;
    us8 q0 = *(const us8*)p;
    us8 q1 = *(const us8*)(p + 16);
    a0 = __builtin_bit_cast(half8, __builtin_shufflevector(q0, q1, 0,2,4,6,8,10,12,14));
    a1 = __builtin_bit_cast(half8, __builtin_shufflevector(q0, q1, 1,3,5,7,9,11,13,15));
}
__device__ __forceinline__ half8 ldw(const unsigned short* p) { return *(const half8*)p; }
__device__ __forceinline__ void mfma6(half8 a0, half8 a1, half8 w0, half8 w1,
                                      f32x4& x0, f32x4& x1) {
    x0 = __builtin_amdgcn_mfma_f32_16x16x32_f16(a0, w0, x0, 0, 0, 0);
    x1 = __builtin_amdgcn_mfma_f32_16x16x32_f16(a0, w1, x1, 0, 0, 0);
    x1 = __builtin_amdgcn_mfma_f32_16x16x32_f16(a1, w0, x1, 0, 0, 0);
}
__device__ __forceinline__ void rwrite1(float* arena, int wave, int lane,
        f32x4 c0, f32x4 c1, f32x4 h0, f32x4 h1) {
    float* b = arena + wave * 512;
    #pragma unroll
    for (int r = 0; r < 4; ++r) {
        b[lane * 4 + r]       = c0[r] + c1[r] * INVS;
        b[256 + lane * 4 + r] = h0[r] + h1[r] * INVS;
    }
}
__device__ __forceinline__ void rsum1(const float* arena, int idx, float& cs, float& hs) {
    float c = 0.f, h = 0.f;
    #pragma unroll
    for (int w = 0; w < 8; ++w) {
        c += arena[w * 512 + idx];
        h += arena[w * 512 + 256 + idx];
    }
    cs = c; hs = h;
}
__device__ __forceinline__ void fstore(char* fa, int offp, float v) {
    _Float16 u0, u1; limbs2(v, u0, u1);
    unsigned pk = (unsigned)__builtin_bit_cast(unsigned short, u0) |
                  ((unsigned)__builtin_bit_cast(unsigned short, u1) << 16);
    __hip_atomic_store((unsigned*)(fa + offp), pk, __ATOMIC_RELAXED, __HIP_MEMORY_SCOPE_AGENT);
}
template<int ACQ>
__device__ __forceinline__ void pollw(unsigned* f, unsigned tgt, int lane) {
    unsigned v = __hip_atomic_load(f + lane, __ATOMIC_RELAXED, __HIP_MEMORY_SCOPE_AGENT);
    while (__ballot(v < tgt)) {
        __builtin_amdgcn_s_sleep(2);
        v = __hip_atomic_load(f + lane, __ATOMIC_RELAXED, __HIP_MEMORY_SCOPE_AGENT);
    }
    if (ACQ)
        (void)__hip_atomic_load(f, __ATOMIC_ACQUIRE, __HIP_MEMORY_SCOPE_AGENT);
}
__device__ __forceinline__ void publish(unsigned* slot, unsigned v) {
    __hip_atomic_store(slot, v, __ATOMIC_RELAXED, __HIP_MEMORY_SCOPE_AGENT);
}

// ------------- x@W0x precompute: XC/XH[t][64][1024] fp32 ---------------------
struct XPK { const float* x; const unsigned short* wf; float* xw; };

__global__ __launch_bounds__(512, 2) void xw0_gemm(XPK p) {
    __shared__ float arena[4096];
    const int tid  = threadIdx.x;
    const int wave = tid >> 6, lane = tid & 63;
    const int l15 = lane & 15, lg = lane >> 4;
    const int lane8 = lane * 8, lg8 = lg * 8;
    const int bx = blockIdx.x;
    const int cg = (bx & 7) * 8 + ((bx >> 3) & 7);
    const int rt = bx >> 6;
    const unsigned short* wf0 = p.wf;
    const int xrow = rt * 16 + l15;
    const int rowf = tid >> 4, colf = tid & 15;
    const size_t opos = (size_t)(rt * 16 + rowf) * NH + cg * 16 + colf;
    const int idx = colf * 4 + (rowf >> 2) * 64 + (rowf & 3);

    for (int t = 0; t < T_STEPS; ++t) {
        const float* xt = p.x + (size_t)t * 65536;
        f32x4 c0 = {}, c1 = {}, h0 = {}, h1 = {};
        half8 xw_[16], xa0[4], xa1[4];
        #pragma unroll
        for (int i = 0; i < 4; ++i) {
            const int ks = wave * 4 + i;
            const unsigned short* pc = wf0 + ((size_t)cg * 64 + ks) * 1024 + lane8;
            const unsigned short* ph = wf0 + ((size_t)(cg + 64) * 64 + ks) * 1024 + lane8;
            xw_[i*4+0] = ldw(pc); xw_[i*4+1] = ldw(pc + 512);
            xw_[i*4+2] = ldw(ph); xw_[i*4+3] = ldw(ph + 512);
            const float* xp = xt + (size_t)xrow * NH + ks * 32 + lg8;
            float4 v0 = *(const float4*)xp, v1 = *(const float4*)(xp + 4);
            float fv[8] = {v0.x, v0.y, v0.z, v0.w, v1.x, v1.y, v1.z, v1.w};
            #pragma unroll
            for (int j = 0; j < 8; ++j) { _Float16 u, w2; limbs2(fv[j], u, w2); xa0[i][j] = u; xa1[i][j] = w2; }
        }
        #pragma unroll
        for (int i = 0; i < 4; ++i) {
            mfma6(xa0[i], xa1[i], xw_[i*4+0], xw_[i*4+1], c0, c1);
            mfma6(xa0[i], xa1[i], xw_[i*4+2], xw_[i*4+3], h0, h1);
        }
        rwrite1(arena, wave, lane, c0, c1, h0, h1);
        LBAR();
        if (tid < 256) {
            float cs, hs; rsum1(arena, idx, cs, hs);
            p.xw[(size_t)t * 131072 + opos]         = cs;
            p.xw[(size_t)t * 131072 + 65536 + opos] = hs;
        }
        __syncthreads();
    }
}

// ------------------------------ persistent kernel ----------------------------
struct PK {
    const float* x; const float* hidden;
    const unsigned short* wf;
    char* fa; unsigned* flags; float* out;
    const float* xw;
};

template<int XPRE>
__global__ __launch_bounds__(512, 2) void persist(PK p) {
    __shared__ unsigned short slab[65536];   // 128 KB: W0h frags
    __shared__ float arena[4096];            // 16 KB reduce arena

    const int tid  = threadIdx.x;
    const int wave = tid >> 6, lane = tid & 63;
    const int l15 = lane & 15, lg = lane >> 4;
    const int lane8 = lane * 8, lg8 = lg * 8;
    const int bx = blockIdx.x;
    const int cg = (bx & 7) * 8 + ((bx >> 3) & 7);
    const int rt = bx >> 6;

    const unsigned short* wf0 = p.wf;
    const unsigned short* wfs[8];
    #pragma unroll
    for (int i = 0; i < 8; ++i) wfs[i] = p.wf + 8388608ull + (size_t)i * 4194304ull;

    char* FAH  = p.fa + (size_t)(0 * 4 + rt) * 65536;
    char* FAS0 = p.fa + (size_t)(1 * 4 + rt) * 65536;
    char* FAS1 = p.fa + (size_t)(2 * 4 + rt) * 65536;
    char* FAS2 = p.fa + (size_t)(3 * 4 + rt) * 65536;
    char* FAS3 = p.fa + (size_t)(4 * 4 + rt) * 65536;
    char* FAS5 = p.fa + (size_t)(5 * 4 + rt) * 65536;
    #define FLG(tn) (p.flags + ((tn) * 4 + rt) * 64)

    #define PFW(dst, wfp) do { \
        _Pragma("unroll") \
        for (int _i = 0; _i < 4; ++_i) { \
            const int _ks = wave * 4 + _i; \
            const unsigned short* _pc = (wfp) + ((size_t)cg * 32 + _ks) * 1024 + lane8; \
            const unsigned short* _ph = (wfp) + ((size_t)(cg + 64) * 32 + _ks) * 1024 + lane8; \
            dst[_i*4+0] = ldw(_pc); dst[_i*4+1] = ldw(_pc + 512); \
            dst[_i*4+2] = ldw(_ph); dst[_i*4+3] = ldw(_ph + 512); } } while (0)
    #define ALD(dst0, dst1, fa) do { \
        _Pragma("unroll") \
        for (int _i = 0; _i < 4; ++_i) aload(fa, wave * 4 + _i, lane, dst0[_i], dst1[_i]); } while (0)
    #define MFM(w, a0v, a1v, X0, X1, Y0, Y1) do { \
        _Pragma("unroll") \
        for (int _i = 0; _i < 4; ++_i) { \
            mfma6(a0v[_i], a1v[_i], w[_i*4+0], w[_i*4+1], X0, X1); \
            mfma6(a0v[_i], a1v[_i], w[_i*4+2], w[_i*4+3], Y0, Y1); } } while (0)

    // ---- fill W0h LDS slab (once) ----
    {
        const u32x4* sc = (const u32x4*)(wf0 + ((size_t)cg * 64 + 32) * 1024);
        const u32x4* sh = (const u32x4*)(wf0 + ((size_t)(cg + 64) * 64 + 32) * 1024);
        u32x4* dst = (u32x4*)slab;
        for (int i = tid; i < 4096; i += 512) { dst[i] = sc[i]; dst[4096 + i] = sh[i]; }
    }

    const int rowf = tid >> 4, colf = tid & 15;
    const size_t opos = (size_t)(rt * 16 + rowf) * NH + cg * 16 + colf;
    const int idx = colf * 4 + (rowf >> 2) * 64 + (rowf & 3);
    int offp;
    {
        int col = cg * 16 + colf;
        int ksp = col >> 5, kin = col & 31;
        int lanep = (kin >> 3) * 16 + rowf;
        offp = (ksp * 64 + lanep) * 32 + (kin & 7) * 4;
    }
    float hprev = 0.f, s0v = 0.f, s1v = 0.f, s2v = 0.f, s3v = 0.f, s5v = 0.f, runsum = 0.f;
    if (tid < 256) hprev = p.hidden[opos];
    const int xrow = rt * 16 + l15;
    __syncthreads();

    for (int t = 0; t < T_STEPS; ++t) {
        const float* xt = p.x + (size_t)t * 65536;

        // ========== L1: x-part (in-kernel or precomputed), then h-part =======
        f32x4 c0 = {}, c1 = {}, h0 = {}, h1 = {};
        float xcv = 0.f, xhv = 0.f;
        if constexpr (XPRE) {
            if (tid < 256) {                        // precomputed x@W0x, pre-poll
                xcv = p.xw[(size_t)t * 131072 + opos];
                xhv = p.xw[(size_t)t * 131072 + 65536 + opos];
            }
            if (wave == 7) pollw<1>(FLG(0), t + 1, lane);    // the step's ONE acquire
        } else {
            half8 xw_[16], xa0[4], xa1[4];
            #pragma unroll
            for (int i = 0; i < 4; ++i) {           // prefetch W0x + load x
                const int ks = wave * 4 + i;
                const unsigned short* pc = wf0 + ((size_t)cg * 64 + ks) * 1024 + lane8;
                const unsigned short* ph = wf0 + ((size_t)(cg + 64) * 64 + ks) * 1024 + lane8;
                xw_[i*4+0] = ldw(pc); xw_[i*4+1] = ldw(pc + 512);
                xw_[i*4+2] = ldw(ph); xw_[i*4+3] = ldw(ph + 512);
                const float* xp = xt + (size_t)xrow * NH + ks * 32 + lg8;
                float4 v0 = *(const float4*)xp, v1 = *(const float4*)(xp + 4);
                float fv[8] = {v0.x, v0.y, v0.z, v0.w, v1.x, v1.y, v1.z, v1.w};
                #pragma unroll
                for (int j = 0; j < 8; ++j) { _Float16 u, w2; limbs2(fv[j], u, w2); xa0[i][j] = u; xa1[i][j] = w2; }
            }
            if (wave == 7) pollw<1>(FLG(0), t + 1, lane);    // the step's ONE acquire
            MFM(xw_, xa0, xa1, c0, c1, h0, h1);
        }
        __syncthreads();                            // acquire ordered before FAH reads
        {
            half8 ha0[4], ha1[4];
            ALD(ha0, ha1, FAH);
            #pragma unroll
            for (int i = 0; i < 4; ++i) {           // W0h from LDS slab
                const int kc = wave * 4 + i;
                const unsigned short* pc = &slab[kc * 1024 + lane8];
                const unsigned short* ph = &slab[(kc + 32) * 1024 + lane8];
                mfma6(ha0[i], ha1[i], *(const half8*)pc, *(const half8*)(pc + 512), c0, c1);
                mfma6(ha0[i], ha1[i], *(const half8*)ph, *(const half8*)(ph + 512), h0, h1);
            }
            rwrite1(arena, wave, lane, c0, c1, h0, h1);
        }
        LBAR();
        if (tid < 256) {
            float cs, hs; rsum1(arena, idx, cs, hs);
            if constexpr (XPRE) { cs += xcv; hs += xhv; }
            s0v = hprev + sigf(cs) * (tanhf(hs) - hprev);
            fstore(FAS0, offp, s0v);
        }
        __syncthreads();
        if (tid == 0) publish(FLG(1) + cg, t + 1);

        // ========== L2: s1 = comb(s0, s0 @ Ws0)  (Ws0 prefetched pre-poll) ===
        {
            half8 w0[16];
            PFW(w0, wfs[0]);
            if (wave == 7) pollw<0>(FLG(1), t + 1, lane);
            __syncthreads();
            half8 a0[4], a1[4];
            ALD(a0, a1, FAS0);
            f32x4 X0 = {}, X1 = {}, Y0 = {}, Y1 = {};
            MFM(w0, a0, a1, X0, X1, Y0, Y1);
            rwrite1(arena, wave, lane, X0, X1, Y0, Y1);
        }
        LBAR();
        if (tid < 256) {
            float cs, hs; rsum1(arena, idx, cs, hs);
            s1v = s0v + sigf(cs) * (sigf(hs) - s0v);
            fstore(FAS1, offp, s1v);
            runsum = s1v;
        }
        __syncthreads();
        if (tid == 0) publish(FLG(2) + cg, t + 1);

        // ========== L3: s2,s3,s4 (Ws1+Ws2 pre-poll; Ws3 under Ws1 MFMAs) =====
        {
            half8 w1[16], w2[16];
            PFW(w1, wfs[1]);
            PFW(w2, wfs[2]);
            if (wave == 7) pollw<0>(FLG(2), t + 1, lane);
            __syncthreads();
            half8 a0[4], a1[4];
            ALD(a0, a1, FAS1);
            f32x4 X0 = {}, X1 = {}, Y0 = {}, Y1 = {};
            MFM(w1, a0, a1, X0, X1, Y0, Y1);
            half8 w3[16];
            PFW(w3, wfs[3]);                        // issue under the arena dance
            rwrite1(arena, wave, lane, X0, X1, Y0, Y1);
            __syncthreads();
            if (tid < 256) {
                float cs, hs; rsum1(arena, idx, cs, hs);
                s2v = s1v + sigf(cs) * (fmaxf(hs, 0.f) - s1v);
                fstore(FAS2, offp, s2v);
            }
            __syncthreads();
            if (tid == 0) publish(FLG(3) + cg, t + 1);
            X0 = (f32x4){}; X1 = (f32x4){}; Y0 = (f32x4){}; Y1 = (f32x4){};
            MFM(w2, a0, a1, X0, X1, Y0, Y1);
            rwrite1(arena, wave, lane, X0, X1, Y0, Y1);
            LBAR();
            if (tid < 256) {
                float cs, hs; rsum1(arena, idx, cs, hs);
                s3v = s1v + sigf(cs) * (fmaxf(hs, 0.f) - s1v);
                fstore(FAS3, offp, s3v);
            }
            __syncthreads();
            if (tid == 0) publish(FLG(4) + cg, t + 1);
            X0 = (f32x4){}; X1 = (f32x4){}; Y0 = (f32x4){}; Y1 = (f32x4){};
            MFM(w3, a0, a1, X0, X1, Y0, Y1);
            rwrite1(arena, wave, lane, X0, X1, Y0, Y1);
            LBAR();
            if (tid < 256) {
                float cs, hs; rsum1(arena, idx, cs, hs);
                float s4v = s1v + sigf(cs) * (hs - s1v);
                runsum += s2v + s3v + s4v;
            }
            __syncthreads();
        }

        // ========== L4: s5 (Ws4, A=s2), s7 (Ws6, A=s3)  (both pre-poll) ======
        {
            half8 w4[16], w6[16];
            PFW(w4, wfs[4]);
            PFW(w6, wfs[6]);
            if (wave == 7) { pollw<0>(FLG(3), t + 1, lane); pollw<0>(FLG(4), t + 1, lane); }
            __syncthreads();
            half8 a0[4], a1[4], b0[4], b1[4];
            ALD(a0, a1, FAS2);
            ALD(b0, b1, FAS3);
            f32x4 X0 = {}, X1 = {}, Y0 = {}, Y1 = {};
            MFM(w4, a0, a1, X0, X1, Y0, Y1);
            f32x4 U0 = {}, U1 = {}, V0 = {}, V1 = {};
            MFM(w6, b0, b1, U0, U1, V0, V1);
            rwrite1(arena, wave, lane, X0, X1, Y0, Y1);
            LBAR();
            if (tid < 256) {
                float cs, hs; rsum1(arena, idx, cs, hs);
                s5v = s2v + sigf(cs) * (tanhf(hs) - s2v);
                fstore(FAS5, offp, s5v);
            }
            __syncthreads();
            if (tid == 0) publish(FLG(5) + cg, t + 1);
            rwrite1(arena, wave, lane, U0, U1, V0, V1);
            LBAR();
            if (tid < 256) {
                float cs, hs; rsum1(arena, idx, cs, hs);
                float s7v = s3v + sigf(cs) * (tanhf(hs) - s3v);
                runsum += s5v + s7v;
            }
            __syncthreads();
        }

        // ========== L5: s6,s8 (Ws5,Ws7, A=s5) + mean -> out[t] ===============
        {
            half8 w5[16], w7[16];
            PFW(w5, wfs[5]);
            PFW(w7, wfs[7]);
            if (wave == 7) pollw<0>(FLG(5), t + 1, lane);
            __syncthreads();
            half8 a0[4], a1[4];
            ALD(a0, a1, FAS5);
            f32x4 X0 = {}, X1 = {}, Y0 = {}, Y1 = {};
            MFM(w5, a0, a1, X0, X1, Y0, Y1);
            f32x4 U0 = {}, U1 = {}, V0 = {}, V1 = {};
            MFM(w7, a0, a1, U0, U1, V0, V1);
            rwrite1(arena, wave, lane, X0, X1, Y0, Y1);
            LBAR();
            float c6 = 0.f, h6 = 0.f;
            if (tid < 256) rsum1(arena, idx, c6, h6);
            LBAR();                                 // readers done before rewrite
            rwrite1(arena, wave, lane, U0, U1, V0, V1);
            LBAR();
            if (tid < 256) {
                float c8, h8; rsum1(arena, idx, c8, h8);
                float s6 = s5v + sigf(c6) * (sigf(h6) - s5v);
                float s8 = s5v + sigf(c8) * (fmaxf(h8, 0.f) - s5v);
                float v = 0.125f * (runsum + s6 + s8);
                p.out[(size_t)t * 65536 + opos] = v;
                fstore(FAH, offp, v);
                hprev = v;
            }
            __syncthreads();
            if (tid == 0) publish(FLG(0) + cg, t + 2);
        }
    }
    #undef FLG
    #undef PFW
    #undef ALD
    #undef MFM
}

// ---------------------------------- host -------------------------------------
extern "C" void kernel_launch(void* const* d_in, const int* in_sizes, int n_in,
                              void* d_out, int out_size, void* d_ws, size_t ws_size,
                              hipStream_t stream) {
    (void)in_sizes; (void)n_in; (void)out_size;
    const float* inputs = (const float*)d_in[0];
    const float* hidden = (const float*)d_in[1];
    const float* W0     = (const float*)d_in[2];
    const float* Ws     = (const float*)d_in[3];
    float* out = (float*)d_out;

    char* base = (char*)d_ws;
    unsigned short* wf = (unsigned short*)base;
    char* fa = base + WF_BYTES;
    unsigned* flags = (unsigned*)(fa + FA_BYTES);
    float* xw = (float*)(fa + FA_BYTES + 8192);

    const size_t NEED_XW = WF_BYTES + FA_BYTES + 8192 + XW_BYTES;   // ~220 MB
    const bool xpre = ws_size >= NEED_XW;

    initk<<<64, 256, 0, stream>>>(hidden, fa, flags);
    preconv<<<10240, 256, 0, stream>>>(Pre{W0, Ws, wf});
    if (xpre) xw0_gemm<<<256, 512, 0, stream>>>(XPK{inputs, wf, xw});

    PK pk{inputs, hidden, wf, fa, flags, out, xpre ? xw : (const float*)0};
    void* args[] = {&pk};
    if (xpre) {
        auto fn = persist<1>;
        if (hipLaunchCooperativeKernel((void*)fn, dim3(256), dim3(512), args, 0, stream) != hipSuccess)
            persist<1><<<256, 512, 0, stream>>>(pk);
    } else {
        auto fn = persist<0>;
        if (hipLaunchCooperativeKernel((void*)fn, dim3(256), dim3(512), args, 0, stream) != hipSuccess)
            persist<0><<<256, 512, 0, stream>>>(pk);
    }
}